// Round 2
// baseline (473.938 us; speedup 1.0000x reference)
//
#include <hip/hip_runtime.h>
#include <hip/hip_bf16.h>
#include <hip/hip_fp16.h>

typedef __attribute__((ext_vector_type(8))) short short8;
typedef __attribute__((ext_vector_type(4))) float f32x4;
typedef __attribute__((ext_vector_type(4))) unsigned short us4;

#define MFMA16(a, b, c) __builtin_amdgcn_mfma_f32_16x16x32_bf16(a, b, c, 0, 0, 0)

__device__ __forceinline__ short f2bf(float f) {
    unsigned u = __float_as_uint(f);
    unsigned r = (u + 0x7fffu + ((u >> 16) & 1u)) >> 16;
    return (short)r;
}
__device__ __forceinline__ float h2f(unsigned short u) {
    __half_raw r; r.x = u;
    return __half2float(__half(r));
}

// ---------------- prep kernels ----------------

__global__ __launch_bounds__(256) void k_wcvt(const float* qkv_w, const float* proj_w,
                                              const float* lsc, short* wq, short* wp,
                                              float* scales) {
    int i = blockIdx.x * 256 + threadIdx.x;
    if (i < 576 * 192) wq[i] = f2bf(qkv_w[i]);
    else {
        int j = i - 576 * 192;
        if (j < 192 * 192) wp[j] = f2bf(proj_w[j]);
    }
    if (blockIdx.x == 0 && threadIdx.x < 6)
        scales[threadIdx.x] = expf(fminf(lsc[threadIdx.x], 4.60517018598809136f));
}

// cpb MLP: 507 entries, 3 -> 512 relu -> 6
__global__ __launch_bounds__(64) void k_tbl(const float* tab, const float* w1, const float* b1,
                                            const float* w2, float* tbl) {
    int e = blockIdx.x;
    int t = threadIdx.x;
    float c0 = tab[e * 3 + 0], c1 = tab[e * 3 + 1], c2 = tab[e * 3 + 2];
    float acc[6] = {0.f, 0.f, 0.f, 0.f, 0.f, 0.f};
    for (int u = t; u < 512; u += 64) {
        float hv = c0 * w1[u * 3 + 0] + c1 * w1[u * 3 + 1] + c2 * w1[u * 3 + 2] + b1[u];
        hv = fmaxf(hv, 0.f);
        #pragma unroll
        for (int hh = 0; hh < 6; ++hh) acc[hh] += hv * w2[hh * 512 + u];
    }
    #pragma unroll
    for (int hh = 0; hh < 6; ++hh) {
        float v = acc[hh];
        for (int off = 32; off > 0; off >>= 1) v += __shfl_xor(v, off, 64);
        if (t == 0) tbl[e * 6 + hh] = v;
    }
}

// cpb_t[h][q][k112] = 16*sigmoid(tbl[rpi[q*98+k]][h]) (fp16), 0 for k>=98
__global__ __launch_bounds__(128) void k_cpb(const float* tbl, const int* rpi, __half* cpb_t) {
    int k = threadIdx.x;
    if (k >= 112) return;
    int q = blockIdx.x % 98, h = blockIdx.x / 98;
    float v = 0.f;
    if (k < 98) {
        float t = tbl[rpi[q * 98 + k] * 6 + h];
        v = 16.f / (1.f + expf(-t));
    }
    cpb_t[(h * 98 + q) * 112 + k] = __float2half(v);
}

// mpad[w][q][k112] = mask[w][q][k], -60000 for k>=98
__global__ __launch_bounds__(128) void k_mpad(const float* mask, float* mpad) {
    int k = threadIdx.x;
    if (k >= 112) return;
    int q = blockIdx.x % 98, w = blockIdx.x / 98;
    float v = (k < 98) ? mask[(w * 98 + q) * 98 + k] : -60000.f;
    mpad[(w * 98 + q) * 112 + k] = v;
}

// ---------------- qkv GEMM with fused l2-normalize epilogue ----------------
__global__ __launch_bounds__(256) void k_qkv(const float* x, const short* wq, const float* qkv_b,
                                             const float* scales, short* qkvo) {
    __shared__ short As[64 * 200];
    __shared__ short Bs[64 * 200];
    int tid = threadIdx.x;
    int mtile = blockIdx.x;
    for (int c = tid; c < 1536; c += 256) {
        int r = c / 24, k0 = (c % 24) * 8;
        const float* src = x + (mtile * 64 + r) * 192 + k0;
        float4 f0 = *(const float4*)src;
        float4 f1 = *(const float4*)(src + 4);
        short8 v;
        v[0] = f2bf(f0.x); v[1] = f2bf(f0.y); v[2] = f2bf(f0.z); v[3] = f2bf(f0.w);
        v[4] = f2bf(f1.x); v[5] = f2bf(f1.y); v[6] = f2bf(f1.z); v[7] = f2bf(f1.w);
        *(short8*)&As[r * 200 + k0] = v;
    }
    int lane = tid & 63, wv = tid >> 6;
    int l16 = lane & 15, q4 = lane >> 4;
    int wr = (wv >> 1) * 32, wc = (wv & 1) * 32;
    // precompute row decomposition (8 output rows per thread)
    int rowoff[8];
    {
        int mybase = mtile * 64 + wr + q4 * 4;
        #pragma unroll
        for (int j = 0; j < 8; ++j) {
            int m = mybase + (j >> 2) * 16 + (j & 3);
            int bb = m / 98;
            int nn = m - bb * 98;
            rowoff[j] = bb * 56448 + nn * 32;
        }
    }
    for (int nt = 0; nt < 9; ++nt) {
        __syncthreads();
        for (int c = tid; c < 1536; c += 256) {
            int r = c / 24, k0 = (c % 24) * 8;
            *(short8*)&Bs[r * 200 + k0] = *(const short8*)(wq + (nt * 64 + r) * 192 + k0);
        }
        __syncthreads();
        f32x4 acc[2][2] = {};
        #pragma unroll
        for (int ks = 0; ks < 6; ++ks) {
            int ko = ks * 32 + q4 * 8;
            short8 a0 = *(const short8*)&As[(wr + l16) * 200 + ko];
            short8 a1 = *(const short8*)&As[(wr + 16 + l16) * 200 + ko];
            short8 b0 = *(const short8*)&Bs[(wc + l16) * 200 + ko];
            short8 b1 = *(const short8*)&Bs[(wc + 16 + l16) * 200 + ko];
            acc[0][0] = MFMA16(a0, b0, acc[0][0]);
            acc[0][1] = MFMA16(a0, b1, acc[0][1]);
            acc[1][0] = MFMA16(a1, b0, acc[1][0]);
            acc[1][1] = MFMA16(a1, b1, acc[1][1]);
        }
        int hw = nt * 2 + (wc >> 5);
        int which = hw / 6;
        int hhq = hw - which * 6;
        float sc = (which == 0) ? scales[hhq] : 1.f;
        int colbase = (which * 6 + hhq) * 3136 + l16;
        float bia0 = qkv_b[nt * 64 + wc + l16];
        float bia1 = qkv_b[nt * 64 + wc + 16 + l16];
        #pragma unroll
        for (int mf = 0; mf < 2; ++mf)
            #pragma unroll
            for (int i = 0; i < 4; ++i) {
                float v0 = acc[mf][0][i] + bia0;
                float v1 = acc[mf][1][i] + bia1;
                if (which < 2) {
                    float ss = v0 * v0 + v1 * v1;
                    ss += __shfl_xor(ss, 1, 16);
                    ss += __shfl_xor(ss, 2, 16);
                    ss += __shfl_xor(ss, 4, 16);
                    ss += __shfl_xor(ss, 8, 16);
                    float rn = sc / fmaxf(sqrtf(ss), 1e-12f);
                    v0 *= rn; v1 *= rn;
                }
                int ro = rowoff[mf * 4 + i];
                qkvo[ro + colbase]      = f2bf(v0);
                qkvo[ro + colbase + 16] = f2bf(v1);
            }
    }
}

// ---------------- fused attention: no LDS, no barriers ----------------
// block = (w, hh, gb): 7 waves (q-tiles), G=4 batches per block.
__global__ __launch_bounds__(448) void k_attn(const short* qkv, const __half* cpb_t,
                                              const float* mpad, short* tmp) {
    int tid = threadIdx.x;
    int wv = tid >> 6;
    int lane = tid & 63;
    int l16 = lane & 15, q4 = lane >> 4;
    int bx = blockIdx.x;          // ((w*6+hh)*8 + gb)
    int gb = bx & 7;
    int wh = bx >> 3;
    int hh = wh % 6, w = wh / 6;

    // bias (depends only on (w,hh,q,k)): load once, keep in 28 regs
    int q = wv * 16 + l16;
    int qc = q < 98 ? q : 97;
    float bias[7][4];
    #pragma unroll
    for (int ct = 0; ct < 7; ++ct) {
        int k0 = ct * 16 + q4 * 4;
        us4 ch = *(const us4*)(cpb_t + (hh * 98 + qc) * 112 + k0);
        float4 mk = *(const float4*)(mpad + (w * 98 + qc) * 112 + k0);
        bias[ct][0] = h2f(ch.x) + mk.x;
        bias[ct][1] = h2f(ch.y) + mk.y;
        bias[ct][2] = h2f(ch.z) + mk.z;
        bias[ct][3] = h2f(ch.w) + mk.w;
    }

    int srcA = ((q4 & 1) * 2) * 16 + l16;
    int srcB = srcA + 16;
    bool hi = (q4 & 2) != 0;

    #pragma unroll 1
    for (int g = 0; g < 4; ++g) {
        int b = (gb * 4 + g) * 64 + w;
        const short* Qp = qkv + ((size_t)b * 18 + hh) * 3136;
        const short* Kp = Qp + 6 * 3136;
        const short* Vp = Qp + 12 * 3136;

        // QK^T swapped: cc[ct] holds S[q = wv*16+l16][k = ct*16 + q4*4 + i]
        short8 qf = *(const short8*)(Qp + (wv * 16 + l16) * 32 + q4 * 8);
        f32x4 zz = {0.f, 0.f, 0.f, 0.f};
        f32x4 cc[7];
        #pragma unroll
        for (int ct = 0; ct < 7; ++ct) {
            short8 kf = *(const short8*)(Kp + (ct * 16 + l16) * 32 + q4 * 8);
            cc[ct] = MFMA16(kf, qf, zz);
        }
        // softmax (row local to 4 lanes: l16, l16+16, l16+32, l16+48)
        float mx = -1e30f;
        #pragma unroll
        for (int ct = 0; ct < 7; ++ct)
            #pragma unroll
            for (int i = 0; i < 4; ++i) {
                float s = cc[ct][i] + bias[ct][i];
                cc[ct][i] = s;
                mx = fmaxf(mx, s);
            }
        mx = fmaxf(mx, __shfl_xor(mx, 16, 64));
        mx = fmaxf(mx, __shfl_xor(mx, 32, 64));
        float sm = 0.f;
        #pragma unroll
        for (int ct = 0; ct < 7; ++ct)
            #pragma unroll
            for (int i = 0; i < 4; ++i) {
                float e = __expf(cc[ct][i] - mx);
                cc[ct][i] = e;
                sm += e;
            }
        sm += __shfl_xor(sm, 16, 64);
        sm += __shfl_xor(sm, 32, 64);
        float ri = 1.f / sm;
        // pack normalized P to bf16 pairs
        int W[7][2];
        #pragma unroll
        for (int ct = 0; ct < 7; ++ct) {
            float a0 = cc[ct][0] * ri, a1 = cc[ct][1] * ri;
            float a2 = cc[ct][2] * ri, a3 = cc[ct][3] * ri;
            asm("v_cvt_pk_bf16_f32 %0, %1, %2" : "=v"(W[ct][0]) : "v"(a0), "v"(a1));
            asm("v_cvt_pk_bf16_f32 %0, %1, %2" : "=v"(W[ct][1]) : "v"(a2), "v"(a3));
        }
        // PV: build A-frags via bpermute, V B-frags direct from global
        f32x4 o0 = zz, o1 = zz;
        #pragma unroll
        for (int km = 0; km < 4; ++km) {
            int A0 = __shfl(W[2 * km][0], srcA, 64), B0 = __shfl(W[2 * km + 1][0], srcA, 64);
            int A1 = __shfl(W[2 * km][1], srcA, 64), B1 = __shfl(W[2 * km + 1][1], srcA, 64);
            int A2 = __shfl(W[2 * km][0], srcB, 64), B2 = __shfl(W[2 * km + 1][0], srcB, 64);
            int A3 = __shfl(W[2 * km][1], srcB, 64), B3 = __shfl(W[2 * km + 1][1], srcB, 64);
            int w0 = hi ? B0 : A0, w1 = hi ? B1 : A1;
            int w2 = hi ? B2 : A2, w3 = hi ? B3 : A3;
            if (km == 3 && q4 >= 2) { w0 = 0; w1 = 0; w2 = 0; w3 = 0; }
            union { int i4[4]; short8 s; } ua;
            ua.i4[0] = w0; ua.i4[1] = w1; ua.i4[2] = w2; ua.i4[3] = w3;
            short8 bv0, bv1;
            #pragma unroll
            for (int j = 0; j < 8; ++j) {
                int r = km * 32 + q4 * 8 + j;
                int rr = (r < 98) ? r : 0;
                int rb = rr * 32 + l16;
                bv0[j] = Vp[rb];
                bv1[j] = Vp[rb + 16];
            }
            o0 = MFMA16(ua.s, bv0, o0);
            o1 = MFMA16(ua.s, bv1, o1);
        }
        // store: C row = q4*4+i -> q_out, col = l16 -> d
        #pragma unroll
        for (int i = 0; i < 4; ++i) {
            int qo = wv * 16 + q4 * 4 + i;
            if (qo < 98) {
                size_t ob = ((size_t)b * 98 + qo) * 192 + hh * 32;
                tmp[ob + l16]      = f2bf(o0[i]);
                tmp[ob + 16 + l16] = f2bf(o1[i]);
            }
        }
    }
}

// ---------------- proj GEMM ----------------
__global__ __launch_bounds__(256) void k_proj(const short* tmp, const short* wp,
                                              const float* proj_b, float* outp) {
    __shared__ short As[64 * 200];
    __shared__ short Bs[64 * 200];
    int tid = threadIdx.x, mtile = blockIdx.x;
    for (int c = tid; c < 1536; c += 256) {
        int r = c / 24, k0 = (c % 24) * 8;
        *(short8*)&As[r * 200 + k0] =
            *(const short8*)(tmp + ((size_t)(mtile * 64 + r)) * 192 + k0);
    }
    int lane = tid & 63, wv = tid >> 6;
    int l16 = lane & 15, q4 = lane >> 4;
    int wr = (wv >> 1) * 32, wc = (wv & 1) * 32;
    for (int nt = 0; nt < 3; ++nt) {
        __syncthreads();
        for (int c = tid; c < 1536; c += 256) {
            int r = c / 24, k0 = (c % 24) * 8;
            *(short8*)&Bs[r * 200 + k0] = *(const short8*)(wp + (nt * 64 + r) * 192 + k0);
        }
        __syncthreads();
        f32x4 acc[2][2] = {};
        #pragma unroll
        for (int ks = 0; ks < 6; ++ks) {
            int ko = ks * 32 + q4 * 8;
            short8 a0 = *(const short8*)&As[(wr + l16) * 200 + ko];
            short8 a1 = *(const short8*)&As[(wr + 16 + l16) * 200 + ko];
            short8 b0 = *(const short8*)&Bs[(wc + l16) * 200 + ko];
            short8 b1 = *(const short8*)&Bs[(wc + 16 + l16) * 200 + ko];
            acc[0][0] = MFMA16(a0, b0, acc[0][0]);
            acc[0][1] = MFMA16(a0, b1, acc[0][1]);
            acc[1][0] = MFMA16(a1, b0, acc[1][0]);
            acc[1][1] = MFMA16(a1, b1, acc[1][1]);
        }
        #pragma unroll
        for (int mf = 0; mf < 2; ++mf)
            #pragma unroll
            for (int nf = 0; nf < 2; ++nf) {
                int cg = nt * 64 + wc + nf * 16 + l16;
                float bia = proj_b[cg];
                int row0 = wr + mf * 16 + q4 * 4;
                #pragma unroll
                for (int i = 0; i < 4; ++i) {
                    int m = mtile * 64 + row0 + i;
                    outp[(size_t)m * 192 + cg] = acc[mf][nf][i] + bia;
                }
            }
    }
}

extern "C" void kernel_launch(void* const* d_in, const int* in_sizes, int n_in,
                              void* d_out, int out_size, void* d_ws, size_t ws_size,
                              hipStream_t stream) {
    const float* x    = (const float*)d_in[0];
    const float* mask = (const float*)d_in[1];
    const float* qkvw = (const float*)d_in[2];
    const float* qkvb = (const float*)d_in[3];
    const float* lsc  = (const float*)d_in[4];
    const float* w1   = (const float*)d_in[5];
    const float* b1   = (const float*)d_in[6];
    const float* w2   = (const float*)d_in[7];
    const float* pw   = (const float*)d_in[8];
    const float* pb   = (const float*)d_in[9];
    const float* tab  = (const float*)d_in[10];
    const int*   rpi  = (const int*)d_in[11];

    char* ws = (char*)d_ws;
    short*  qkvo   = (short*)(ws + 0);               // 231,211,008
    short*  tmp    = (short*)(ws + 231211008LL);     //  77,070,336
    short*  wq     = (short*)(ws + 308281344LL);     //     221,184
    short*  wp     = (short*)(ws + 308502528LL);     //      73,728
    float*  tbl    = (float*)(ws + 308576256LL);     //      12,288
    float*  scales = (float*)(ws + 308588544LL);     //         256
    __half* cpb_t  = (__half*)(ws + 308588800LL);    //     135,168
    float*  mpad   = (float*)(ws + 308723968LL);     //   2,809,856 (end 311,533,824)
    float*  outp   = (float*)d_out;

    k_wcvt<<<576, 256, 0, stream>>>(qkvw, pw, lsc, wq, wp, scales);
    k_tbl<<<507, 64, 0, stream>>>(tab, w1, b1, w2, tbl);
    k_cpb<<<588, 128, 0, stream>>>(tbl, rpi, cpb_t);
    k_mpad<<<6272, 128, 0, stream>>>(mask, mpad);
    k_qkv<<<3136, 256, 0, stream>>>(x, wq, qkvb, scales, qkvo);
    k_attn<<<3072, 448, 0, stream>>>(qkvo, cpb_t, mpad, tmp);
    k_proj<<<3136, 256, 0, stream>>>(tmp, wp, pb, outp);
}